// Round 12
// baseline (1360.629 us; speedup 1.0000x reference)
//
#include <hip/hip_runtime.h>
#include <math.h>

#define BB 16
#define CC 256
#define NN 2048
#define HH 64
#define ATTSC 4096.0f
#define ATTINV (1.0f/4096.0f)
#define SQRTL2E 1.2011224087864498f   // sqrt(log2(e)); q scaled -> S' = S*log2e
#define NEGB (-1.0e30f)
#define POSB (1.0e30f)

typedef _Float16 f16x8 __attribute__((ext_vector_type(8)));
typedef float f32x4 __attribute__((ext_vector_type(4)));

__device__ __forceinline__ f32x4 mfma16(f16x8 a, f16x8 b, f32x4 c) {
  return __builtin_amdgcn_mfma_f32_16x16x32_f16(a, b, c, 0, 0, 0);
}
__device__ __forceinline__ unsigned short f2h(float f) {
  _Float16 h = (_Float16)f;
  return __builtin_bit_cast(unsigned short, h);
}
__device__ __forceinline__ float h2f(unsigned short u) {
  return (float)__builtin_bit_cast(_Float16, u);
}
__device__ __forceinline__ unsigned pkrtz(float a, float b) {
  auto h = __builtin_amdgcn_cvt_pkrtz(a, b);   // __fp16 ext_vector(2)
  return __builtin_bit_cast(unsigned, h);
}
// Swizzled LDS accessor: row stride 128B, byte ^= ((row&7)<<4)  (T2)
__device__ __forceinline__ unsigned short* sp(unsigned short* base, int row, int colh) {
  return (unsigned short*)((char*)base + (row << 7) + (((colh << 1)) ^ ((row & 7) << 4)));
}
__device__ __forceinline__ const unsigned short* spc(const unsigned short* base, int row, int colh) {
  return (const unsigned short*)((const char*)base + (row << 7) + (((colh << 1)) ^ ((row & 7) << 4)));
}

// ---------------------------------------------------------------------------
__global__ __launch_bounds__(256)
void castw_kernel(const float* __restrict__ in, unsigned short* __restrict__ out,
                  int n, float scale)
{
  const int i = blockIdx.x*256 + threadIdx.x;
  if (i < n) out[i] = f2h(in[i]*scale);
}

// ---------------------------------------------------------------------------
// transpose-cast: src fp32 [b][C][N] -> dst f16 [B][N][C]  (input stage only)
// ---------------------------------------------------------------------------
__global__ __launch_bounds__(256)
void tcast_kernel(const float* __restrict__ src, long sstride,
                  unsigned short* __restrict__ dst)
{
  const int b = blockIdx.z, n0 = blockIdx.x*64, c0 = blockIdx.y*64;
  const int t = threadIdx.x;
  __shared__ float tile[64][66];   // [c][n]
  const float* sb = src + (long)b*sstride;
  #pragma unroll
  for (int p = 0; p < 4; p++) {
    const int cr = (t>>4) + p*16;
    const int nq = (t&15)*4;
    const float4 v = *(const float4*)&sb[(long)(c0+cr)*NN + n0 + nq];
    tile[cr][nq+0] = v.x; tile[cr][nq+1] = v.y;
    tile[cr][nq+2] = v.z; tile[cr][nq+3] = v.w;
  }
  __syncthreads();
  unsigned short* db = dst + (long)b*NN*CC;
  #pragma unroll
  for (int p = 0; p < 4; p++) {
    const int nr = (t>>4) + p*16;
    const int cq = (t&15)*4;
    ushort4 o;
    o.x = f2h(tile[cq+0][nr]); o.y = f2h(tile[cq+1][nr]);
    o.z = f2h(tile[cq+2][nr]); o.w = f2h(tile[cq+3][nr]);
    *(ushort4*)&db[(long)(n0+nr)*CC + c0 + cq] = o;
  }
}

// ---------------------------------------------------------------------------
// GEMM (A-major n): D[n][o] = sum_c A[n][c] * W[o][c] (+bias[o]); out f16
// ---------------------------------------------------------------------------
__global__ __launch_bounds__(256)
void gemm_xw_kernel(const unsigned short* __restrict__ A,
                    const unsigned short* __restrict__ W,
                    const float* __restrict__ bias,
                    unsigned short* __restrict__ out, int ocols)
{
  const int n0 = blockIdx.x*64, o0 = blockIdx.y*64, b = blockIdx.z;
  const int t = threadIdx.x;
  const int w = t >> 6, l = t & 63, lr = l & 15, lg = l >> 4;
  const int wr = w >> 1, wc = w & 1;
  __shared__ unsigned short Al[64][72];
  __shared__ unsigned short Bl[64][72];
  const unsigned short* Ab = A + ((long)b*NN + n0)*CC;
  const int srow = t >> 3, sg = t & 7;
  f32x4 acc[2][2];
  #pragma unroll
  for (int i = 0; i < 2; i++)
    #pragma unroll
    for (int j = 0; j < 2; j++) acc[i][j] = f32x4{0.f,0.f,0.f,0.f};

  for (int kt = 0; kt < 4; kt++) {
    const int k0 = kt*64;
    const uint4 a0 = *(const uint4*)&Ab[(long)srow*CC + k0 + sg*8];
    const uint4 a1 = *(const uint4*)&Ab[(long)(srow+32)*CC + k0 + sg*8];
    const uint4 w0 = *(const uint4*)&W[(long)(o0+srow)*CC + k0 + sg*8];
    const uint4 w1 = *(const uint4*)&W[(long)(o0+srow+32)*CC + k0 + sg*8];
    __syncthreads();
    *(uint4*)&Al[srow][sg*8] = a0;  *(uint4*)&Al[srow+32][sg*8] = a1;
    *(uint4*)&Bl[srow][sg*8] = w0;  *(uint4*)&Bl[srow+32][sg*8] = w1;
    __syncthreads();
    #pragma unroll
    for (int kf = 0; kf < 2; kf++) {
      f16x8 af0 = *(const f16x8*)&Al[wr*32 + lr]     [kf*32 + lg*8];
      f16x8 af1 = *(const f16x8*)&Al[wr*32 + 16 + lr][kf*32 + lg*8];
      f16x8 bf0 = *(const f16x8*)&Bl[wc*32 + lr]     [kf*32 + lg*8];
      f16x8 bf1 = *(const f16x8*)&Bl[wc*32 + 16 + lr][kf*32 + lg*8];
      acc[0][0] = mfma16(af0, bf0, acc[0][0]);
      acc[0][1] = mfma16(af0, bf1, acc[0][1]);
      acc[1][0] = mfma16(af1, bf0, acc[1][0]);
      acc[1][1] = mfma16(af1, bf1, acc[1][1]);
    }
  }
  #pragma unroll
  for (int j = 0; j < 2; j++) {
    const int oc = o0 + wc*32 + j*16 + lr;
    const float bo = bias ? bias[oc] : 0.f;
    #pragma unroll
    for (int i = 0; i < 2; i++) {
      const int nb = n0 + wr*32 + i*16 + lg*4;
      #pragma unroll
      for (int r = 0; r < 4; r++)
        out[((long)b*NN + nb + r)*ocols + oc] = f2h(acc[i][j][r] + bo);
    }
  }
}

// ---------------------------------------------------------------------------
// GEMM with fused diff: A[n][c] = X[n][c] - XR[n][c]*inv(n);
// inv = 1/(1e-9+csum[n]). D[n][o] = sum_c A*W + bias -> out f16 [B][N][CC]
// ---------------------------------------------------------------------------
__global__ __launch_bounds__(256)
void gemm_dxw_kernel(const unsigned short* __restrict__ X,
                     const unsigned short* __restrict__ XR,
                     const float* __restrict__ csumv,
                     const unsigned short* __restrict__ W,
                     const float* __restrict__ bias,
                     unsigned short* __restrict__ out)
{
  const int n0 = blockIdx.x*64, o0 = blockIdx.y*64, b = blockIdx.z;
  const int t = threadIdx.x;
  const int w = t >> 6, l = t & 63, lr = l & 15, lg = l >> 4;
  const int wr = w >> 1, wc = w & 1;
  __shared__ unsigned short Al[64][72];
  __shared__ unsigned short Bl[64][72];
  const unsigned short* Xb  = X  + ((long)b*NN + n0)*CC;
  const unsigned short* XRb = XR + ((long)b*NN + n0)*CC;
  const int srow = t >> 3, sg = t & 7;
  const long nrow0 = (long)b*NN + n0 + srow;
  const float inv0 = 1.f/(1e-9f + csumv[nrow0]);
  const float inv1 = 1.f/(1e-9f + csumv[nrow0+32]);
  f32x4 acc[2][2];
  #pragma unroll
  for (int i = 0; i < 2; i++)
    #pragma unroll
    for (int j = 0; j < 2; j++) acc[i][j] = f32x4{0.f,0.f,0.f,0.f};

  for (int kt = 0; kt < 4; kt++) {
    const int k0 = kt*64;
    const uint4 xa  = *(const uint4*)&Xb [(long)srow*CC + k0 + sg*8];
    const uint4 xra = *(const uint4*)&XRb[(long)srow*CC + k0 + sg*8];
    const uint4 xb_ = *(const uint4*)&Xb [(long)(srow+32)*CC + k0 + sg*8];
    const uint4 xrb = *(const uint4*)&XRb[(long)(srow+32)*CC + k0 + sg*8];
    const uint4 w0 = *(const uint4*)&W[(long)(o0+srow)*CC + k0 + sg*8];
    const uint4 w1 = *(const uint4*)&W[(long)(o0+srow+32)*CC + k0 + sg*8];
    uint4 da, db_;
    {
      const unsigned short* xs = (const unsigned short*)&xa;
      const unsigned short* rs = (const unsigned short*)&xra;
      unsigned short* ds = (unsigned short*)&da;
      #pragma unroll
      for (int j = 0; j < 8; j++) ds[j] = f2h(h2f(xs[j]) - h2f(rs[j])*inv0);
      xs = (const unsigned short*)&xb_;
      rs = (const unsigned short*)&xrb;
      ds = (unsigned short*)&db_;
      #pragma unroll
      for (int j = 0; j < 8; j++) ds[j] = f2h(h2f(xs[j]) - h2f(rs[j])*inv1);
    }
    __syncthreads();
    *(uint4*)&Al[srow][sg*8] = da;  *(uint4*)&Al[srow+32][sg*8] = db_;
    *(uint4*)&Bl[srow][sg*8] = w0;  *(uint4*)&Bl[srow+32][sg*8] = w1;
    __syncthreads();
    #pragma unroll
    for (int kf = 0; kf < 2; kf++) {
      f16x8 af0 = *(const f16x8*)&Al[wr*32 + lr]     [kf*32 + lg*8];
      f16x8 af1 = *(const f16x8*)&Al[wr*32 + 16 + lr][kf*32 + lg*8];
      f16x8 bf0 = *(const f16x8*)&Bl[wc*32 + lr]     [kf*32 + lg*8];
      f16x8 bf1 = *(const f16x8*)&Bl[wc*32 + 16 + lr][kf*32 + lg*8];
      acc[0][0] = mfma16(af0, bf0, acc[0][0]);
      acc[0][1] = mfma16(af0, bf1, acc[0][1]);
      acc[1][0] = mfma16(af1, bf0, acc[1][0]);
      acc[1][1] = mfma16(af1, bf1, acc[1][1]);
    }
  }
  #pragma unroll
  for (int j = 0; j < 2; j++) {
    const int oc = o0 + wc*32 + j*16 + lr;
    const float bo = bias[oc];
    #pragma unroll
    for (int i = 0; i < 2; i++) {
      const int nb = n0 + wr*32 + i*16 + lg*4;
      #pragma unroll
      for (int r = 0; r < 4; r++)
        out[((long)b*NN + nb + r)*CC + oc] = f2h(acc[i][j][r] + bo);
    }
  }
}

// ---------------------------------------------------------------------------
// GEMM (W-major o): out[o][n] = sum_c W[o][c]*X[n][c] + bias[o]; f16 [B][CC][NN]
// ---------------------------------------------------------------------------
__global__ __launch_bounds__(256)
void gemm_wx_kernel(const unsigned short* __restrict__ W,
                    const unsigned short* __restrict__ X,
                    const float* __restrict__ bias,
                    unsigned short* __restrict__ out)
{
  const int n0 = blockIdx.x*64, o0 = blockIdx.y*64, b = blockIdx.z;
  const int t = threadIdx.x;
  const int w = t >> 6, l = t & 63, lr = l & 15, lg = l >> 4;
  const int wr = w >> 1, wc = w & 1;
  __shared__ unsigned short Al[64][72];
  __shared__ unsigned short Bl[64][72];
  const unsigned short* Xb = X + ((long)b*NN + n0)*CC;
  const int srow = t >> 3, sg = t & 7;
  f32x4 acc[2][2];
  #pragma unroll
  for (int i = 0; i < 2; i++)
    #pragma unroll
    for (int j = 0; j < 2; j++) acc[i][j] = f32x4{0.f,0.f,0.f,0.f};

  for (int kt = 0; kt < 4; kt++) {
    const int k0 = kt*64;
    const uint4 w0 = *(const uint4*)&W[(long)(o0+srow)*CC + k0 + sg*8];
    const uint4 w1 = *(const uint4*)&W[(long)(o0+srow+32)*CC + k0 + sg*8];
    const uint4 x0 = *(const uint4*)&Xb[(long)srow*CC + k0 + sg*8];
    const uint4 x1 = *(const uint4*)&Xb[(long)(srow+32)*CC + k0 + sg*8];
    __syncthreads();
    *(uint4*)&Al[srow][sg*8] = w0;  *(uint4*)&Al[srow+32][sg*8] = w1;
    *(uint4*)&Bl[srow][sg*8] = x0;  *(uint4*)&Bl[srow+32][sg*8] = x1;
    __syncthreads();
    #pragma unroll
    for (int kf = 0; kf < 2; kf++) {
      f16x8 af0 = *(const f16x8*)&Al[wr*32 + lr]     [kf*32 + lg*8];
      f16x8 af1 = *(const f16x8*)&Al[wr*32 + 16 + lr][kf*32 + lg*8];
      f16x8 bf0 = *(const f16x8*)&Bl[wc*32 + lr]     [kf*32 + lg*8];
      f16x8 bf1 = *(const f16x8*)&Bl[wc*32 + 16 + lr][kf*32 + lg*8];
      acc[0][0] = mfma16(af0, bf0, acc[0][0]);
      acc[0][1] = mfma16(af0, bf1, acc[0][1]);
      acc[1][0] = mfma16(af1, bf0, acc[1][0]);
      acc[1][1] = mfma16(af1, bf1, acc[1][1]);
    }
  }
  #pragma unroll
  for (int j = 0; j < 2; j++) {
    const int nc = n0 + wc*32 + j*16 + lr;
    #pragma unroll
    for (int i = 0; i < 2; i++) {
      #pragma unroll
      for (int r = 0; r < 4; r++) {
        const int oc = o0 + wr*32 + i*16 + lg*4 + r;
        out[((long)b*CC + oc)*NN + nc] = f2h(acc[i][j][r] + bias[oc]);
      }
    }
  }
}

// ---------------------------------------------------------------------------
// rowstat (exp2 domain): per (b,n) over all m: log2-domain max & 1/sum of
// exp2(masked S'[n,m]). Dead rows -> rmax=+1e30.
// ---------------------------------------------------------------------------
__global__ __launch_bounds__(256)
void rowstat_kernel(const unsigned short* __restrict__ qT, const int* __restrict__ mask,
                    float* __restrict__ rmax, float* __restrict__ rinv)
{
  const int b = blockIdx.y, n0 = blockIdx.x*64;
  const int t = threadIdx.x, w = t>>6, l = t&63, lr = l&15, lg = l>>4;
  __shared__ unsigned short qs[64*64];
  __shared__ int ml[64];
  const int srow = t>>3, sg = t&7;
  const unsigned short* qbase = qT + (long)b*NN*HH;
  *(uint4*)sp(qs, srow,    sg*8) = *(const uint4*)&qbase[(long)(n0+srow)*HH + sg*8];
  *(uint4*)sp(qs, srow+32, sg*8) = *(const uint4*)&qbase[(long)(n0+srow+32)*HH + sg*8];
  int maskn[4];
  #pragma unroll
  for (int r = 0; r < 4; r++) maskn[r] = mask[(long)b*NN + n0 + w*16 + lg*4 + r];
  __syncthreads();
  f16x8 af0 = *(const f16x8*)spc(qs, w*16 + lr, lg*8);
  f16x8 af1 = *(const f16x8*)spc(qs, w*16 + lr, 32 + lg*8);
  float mx[4], sm[4];
  #pragma unroll
  for (int r = 0; r < 4; r++) { mx[r] = -INFINITY; sm[r] = 0.f; }

  for (int m0 = 0; m0 < NN; m0 += 64) {
    __syncthreads();
    *(uint4*)sp(qs, srow,    sg*8) = *(const uint4*)&qbase[(long)(m0+srow)*HH + sg*8];
    *(uint4*)sp(qs, srow+32, sg*8) = *(const uint4*)&qbase[(long)(m0+srow+32)*HH + sg*8];
    if (t < 64) ml[t] = mask[(long)b*NN + m0 + t];
    __syncthreads();
    float sv[4][4];
    #pragma unroll
    for (int tm = 0; tm < 4; tm++) {
      f32x4 s = f32x4{0.f,0.f,0.f,0.f};
      s = mfma16(af0, *(const f16x8*)spc(qs, tm*16 + lr, lg*8),      s);
      s = mfma16(af1, *(const f16x8*)spc(qs, tm*16 + lr, 32 + lg*8), s);
      const int cm = ml[tm*16 + lr];
      #pragma unroll
      for (int r = 0; r < 4; r++) sv[tm][r] = (maskn[r] && cm) ? s[r] : NEGB;
    }
    #pragma unroll
    for (int r = 0; r < 4; r++) {
      const float tmx = fmaxf(fmaxf(sv[0][r], sv[1][r]), fmaxf(sv[2][r], sv[3][r]));
      const float nm  = fmaxf(mx[r], tmx);
      sm[r] = sm[r]*exp2f(mx[r]-nm)
            + exp2f(sv[0][r]-nm) + exp2f(sv[1][r]-nm)
            + exp2f(sv[2][r]-nm) + exp2f(sv[3][r]-nm);
      mx[r] = nm;
    }
  }
  #pragma unroll
  for (int off = 1; off < 16; off <<= 1) {
    #pragma unroll
    for (int r = 0; r < 4; r++) {
      const float om = __shfl_xor(mx[r], off, 64);
      const float os = __shfl_xor(sm[r], off, 64);
      const float nm = fmaxf(mx[r], om);
      sm[r] = sm[r]*exp2f(mx[r]-nm) + os*exp2f(om-nm);
      mx[r] = nm;
    }
  }
  if (lr == 0) {
    #pragma unroll
    for (int r = 0; r < 4; r++) {
      const long idx = (long)b*NN + n0 + w*16 + lg*4 + r;
      rmax[idx] = maskn[r] ? mx[r] : POSB;   // dead row: exp2(s-POSB)=0 in yatt
      rinv[idx] = 1.f/sm[r];
    }
  }
}

// ---------------------------------------------------------------------------
// yatt: R6 schedule (grid 512, m-tile 64, full c, 3 barriers/chunk) with the
// swap's micro-wins kept, but qm B-frags in a third swizzled LDS tile instead
// of 32 VGPRs (R11's VGPR=132 crossed the 128 occupancy cliff -> 11% occ).
// __launch_bounds__(256,4) pins the allocator under 128 VGPRs.
// ---------------------------------------------------------------------------
__global__ __launch_bounds__(256, 4)
void yatt_kernel(const unsigned short* __restrict__ qT, const unsigned short* __restrict__ xv,
                 const int* __restrict__ mask, const float* __restrict__ rmax,
                 const float* __restrict__ rinv, unsigned short* __restrict__ xrTh,
                 float* __restrict__ csum)
{
  const int bid = blockIdx.x;
  const int swz = (bid & 7)*64 + (bid >> 3);   // 512 = 8 XCD x 64
  const int b  = swz >> 5;
  const int m0 = (swz & 31) * 64;
  const int t = threadIdx.x, w = t>>6, l = t&63, lr = l&15, lg = l>>4;

  __shared__ unsigned short qm[64*64];   // 8 KB swizzled [m][h], block-constant
  __shared__ unsigned short qn[64*64];   // 8 KB swizzled [n][h]
  __shared__ unsigned short at[64*64];   // 8 KB swizzled [m][n]
  __shared__ float csred[4][4][16];

  const unsigned short* qbase = qT + (long)b*NN*HH;
  const unsigned short* xvb = xv + (long)b*CC*NN;
  const int srow = t>>3, sg = t&7;

  // stage qm once + column-mask (block-constant)
  *(uint4*)sp(qm, srow,    sg*8) = *(const uint4*)&qbase[(long)(m0+srow)*HH + sg*8];
  *(uint4*)sp(qm, srow+32, sg*8) = *(const uint4*)&qbase[(long)(m0+srow+32)*HH + sg*8];
  float mcf[4];
  #pragma unroll
  for (int tm = 0; tm < 4; tm++)
    mcf[tm] = mask[(long)b*NN + m0 + tm*16 + lr] ? 1.f : 0.f;

  f32x4 acc[4][4];
  #pragma unroll
  for (int mi = 0; mi < 4; mi++)
    #pragma unroll
    for (int ci = 0; ci < 4; ci++) acc[mi][ci] = f32x4{0.f,0.f,0.f,0.f};
  float cs[4] = {0.f, 0.f, 0.f, 0.f};
  const int nb = w*16 + lg*4;    // thread's 4 n rows within chunk

  for (int nc = 0; nc < NN; nc += 64) {
    __syncthreads();   // prev S (qn readers) + prev PV (at readers) done; qm staged
    *(uint4*)sp(qn, srow,    sg*8) = *(const uint4*)&qbase[(long)(nc+srow)*HH + sg*8];
    *(uint4*)sp(qn, srow+32, sg*8) = *(const uint4*)&qbase[(long)(nc+srow+32)*HH + sg*8];
    const float4 rm4 = *(const float4*)&rmax[(long)b*NN + nc + nb];
    const float4 ri4 = *(const float4*)&rinv[(long)b*NN + nc + nb];
    const int4   mn4 = *(const int4*)&mask[(long)b*NN + nc + nb];
    // xv B-frags issued early (T14); L2-resident, latency hides under staging
    f16x8 xb0[4], xb1[4];
    #pragma unroll
    for (int ci = 0; ci < 4; ci++) {
      const unsigned short* xp = &xvb[(long)(w*64 + ci*16 + lr)*NN + nc];
      xb0[ci] = *(const f16x8*)(xp + lg*8);
      xb1[ci] = *(const f16x8*)(xp + 32 + lg*8);
    }
    __syncthreads();   // qn staged
    const float rmv[4] = {rm4.x, rm4.y, rm4.z, rm4.w};
    const float rvs[4] = {ri4.x*ATTSC, ri4.y*ATTSC, ri4.z*ATTSC, ri4.w*ATTSC};
    const float dsc[4] = {mn4.x ? 0.f : rvs[0], mn4.y ? 0.f : rvs[1],
                          mn4.z ? 0.f : rvs[2], mn4.w ? 0.f : rvs[3]};
    // S: D[n][m] via A-frag = qn (wave's 16 n-rows), B-frag = qm from LDS
    const f16x8 a0 = *(const f16x8*)spc(qn, w*16 + lr, lg*8);
    const f16x8 a1 = *(const f16x8*)spc(qn, w*16 + lr, 32 + lg*8);
    #pragma unroll
    for (int tm = 0; tm < 4; tm++) {
      const f16x8 bq0 = *(const f16x8*)spc(qm, tm*16 + lr, lg*8);
      const f16x8 bq1 = *(const f16x8*)spc(qm, tm*16 + lr, 32 + lg*8);
      f32x4 s = mfma16(a0, bq0, f32x4{0.f,0.f,0.f,0.f});
      s = mfma16(a1, bq1, s);
      const float c0 = rvs[0]*mcf[tm], c1 = rvs[1]*mcf[tm];
      const float c2 = rvs[2]*mcf[tm], c3 = rvs[3]*mcf[tm];
      const float a0_ = exp2f(s[0]-rmv[0])*c0 + dsc[0];
      const float a1_ = exp2f(s[1]-rmv[1])*c1 + dsc[1];
      const float a2_ = exp2f(s[2]-rmv[2])*c2 + dsc[2];
      const float a3_ = exp2f(s[3]-rmv[3])*c3 + dsc[3];
      cs[tm] += (a0_ + a1_) + (a2_ + a3_);
      uint2 pk;
      pk.x = pkrtz(a0_, a1_);
      pk.y = pkrtz(a2_, a3_);
      *(uint2*)sp(at, tm*16 + lr, nb) = pk;   // 4 consecutive n at fixed m
    }
    __syncthreads();   // at ready
    // PV: acc[m][c] += at[m][n'] * xv[c][n']
    #pragma unroll
    for (int mi = 0; mi < 4; mi++) {
      const f16x8 aa0 = *(const f16x8*)spc(at, mi*16 + lr, lg*8);
      const f16x8 aa1 = *(const f16x8*)spc(at, mi*16 + lr, 32 + lg*8);
      #pragma unroll
      for (int ci = 0; ci < 4; ci++) {
        acc[mi][ci] = mfma16(aa0, xb0[ci], acc[mi][ci]);
        acc[mi][ci] = mfma16(aa1, xb1[ci], acc[mi][ci]);
      }
    }
  }

  #pragma unroll
  for (int mi = 0; mi < 4; mi++)
    #pragma unroll
    for (int ci = 0; ci < 4; ci++)
      #pragma unroll
      for (int r = 0; r < 4; r++)
        xrTh[((long)b*NN + m0 + mi*16 + lg*4 + r)*CC + w*64 + ci*16 + lr] =
            f2h(acc[mi][ci][r] * ATTINV);

  #pragma unroll
  for (int tm = 0; tm < 4; tm++) {
    cs[tm] += __shfl_xor(cs[tm], 16, 64);
    cs[tm] += __shfl_xor(cs[tm], 32, 64);
    if (lg == 0) csred[tm][w][lr] = cs[tm];
  }
  __syncthreads();
  if (t < 64) {
    const int tm = t >> 4, mr = t & 15;
    const float v = csred[tm][0][mr] + csred[tm][1][mr]
                  + csred[tm][2][mr] + csred[tm][3][mr];
    csum[(long)b*NN + m0 + tm*16 + mr] = v * ATTINV;
  }
}

// ---------------------------------------------------------------------------
// BN stats over [B*N][C] f16, two-stage deterministic
// ---------------------------------------------------------------------------
__global__ __launch_bounds__(256)
void bnstatsA_kernel(const unsigned short* __restrict__ tTh, float* __restrict__ part)
{
  const int k = blockIdx.x;
  const int c = threadIdx.x;
  float s = 0.f, sq = 0.f;
  const long r0 = (long)k*128;
  for (int r = 0; r < 128; r++) {
    const float v = h2f(tTh[(r0 + r)*CC + c]);
    s += v; sq += v*v;
  }
  part[(long)k*CC + c] = s;
  part[(long)(256 + k)*CC + c] = sq;
}

__global__ __launch_bounds__(1024)
void bnstatsB_kernel(const float* __restrict__ part,
                     float* __restrict__ mean, float* __restrict__ istd)
{
  const int t = threadIdx.x, c = t & 255, q = t >> 8;
  float s = 0.f, sq = 0.f;
  for (int k = q*64; k < q*64 + 64; k++) {
    s  += part[(long)k*CC + c];
    sq += part[(long)(256 + k)*CC + c];
  }
  __shared__ float ls[4][256], lq[4][256];
  ls[q][c] = s; lq[q][c] = sq;
  __syncthreads();
  if (q == 0) {
    s  = ls[0][c] + ls[1][c] + ls[2][c] + ls[3][c];
    sq = lq[0][c] + lq[1][c] + lq[2][c] + lq[3][c];
    const float mu = s / (float)(BB*NN);
    mean[c] = mu;
    istd[c] = rsqrtf(sq/(float)(BB*NN) - mu*mu + 1e-5f);
  }
}

// ---------------------------------------------------------------------------
// bnapplyA: xTo[p][c] = f16(relu(bn(tTh[p][c])))
// ---------------------------------------------------------------------------
__global__ __launch_bounds__(256)
void bnapplyA_kernel(const unsigned short* __restrict__ tTh, const float* __restrict__ mean,
                     const float* __restrict__ istd, const float* __restrict__ g,
                     const float* __restrict__ bt, unsigned short* __restrict__ xTo)
{
  __shared__ float sc[CC], sh[CC];
  const int t = threadIdx.x;
  {
    const float is = istd[t], gg = g[t];
    sc[t] = is*gg; sh[t] = bt[t] - mean[t]*is*gg;
  }
  __syncthreads();
  const long i = (long)blockIdx.x*256 + t;
  const long base = i*8;
  const int c8 = (int)(base & 255);
  const uint4 v = *(const uint4*)&tTh[base];
  const unsigned short* hs = (const unsigned short*)&v;
  uint4 ou;
  unsigned short* os = (unsigned short*)&ou;
  #pragma unroll
  for (int j = 0; j < 8; j++)
    os[j] = f2h(fmaxf(h2f(hs[j])*sc[c8+j] + sh[c8+j], 0.f));
  *(uint4*)&xTo[base] = ou;
}

// ---------------------------------------------------------------------------
// bnfuse: tTh f16 [n][c] -> out fp32 [c][n] = relu(bn)+resid, plus optional
// xtn f16 [n][c] for the next layer.
// ---------------------------------------------------------------------------
__global__ __launch_bounds__(256)
void bnfuse_kernel(const unsigned short* __restrict__ tTh, const float* __restrict__ mean,
                   const float* __restrict__ istd, const float* __restrict__ g,
                   const float* __restrict__ bt, const float* __restrict__ resid,
                   long rstride, float* __restrict__ outp, long ostride,
                   unsigned short* __restrict__ xtn)
{
  const int b = blockIdx.z, n0 = blockIdx.x*64, c0 = blockIdx.y*64;
  const int t = threadIdx.x;
  __shared__ float tile[64][66];
  const unsigned short* tb_ = tTh + ((long)b*NN + n0)*CC;
  const int cq = (t&15)*4;
  float scv[4], shv[4];
  #pragma unroll
  for (int j = 0; j < 4; j++) {
    const int c = c0 + cq + j;
    const float is = istd[c], gg = g[c];
    scv[j] = is*gg; shv[j] = bt[c] - mean[c]*is*gg;
  }
  #pragma unroll
  for (int p = 0; p < 4; p++) {
    const int nr = (t>>4) + p*16;
    const ushort4 v = *(const ushort4*)&tb_[(long)nr*CC + c0 + cq];
    tile[cq+0][nr] = fmaxf(h2f(v.x)*scv[0] + shv[0], 0.f);
    tile[cq+1][nr] = fmaxf(h2f(v.y)*scv[1] + shv[1], 0.f);
    tile[cq+2][nr] = fmaxf(h2f(v.z)*scv[2] + shv[2], 0.f);
    tile[cq+3][nr] = fmaxf(h2f(v.w)*scv[3] + shv[3], 0.f);
  }
  __syncthreads();
  const int nq = (t&15)*4;
  #pragma unroll
  for (int p = 0; p < 4; p++) {
    const int cr = (t>>4) + p*16;
    float4 o;
    o.x = tile[cr][nq+0]; o.y = tile[cr][nq+1];
    o.z = tile[cr][nq+2]; o.w = tile[cr][nq+3];
    if (resid) {
      const float4 rv = *(const float4*)&resid[(long)b*rstride + (long)(c0+cr)*NN + n0 + nq];
      o.x += rv.x; o.y += rv.y; o.z += rv.z; o.w += rv.w;
    }
    *(float4*)&outp[(long)b*ostride + (long)(c0+cr)*NN + n0 + nq] = o;
    tile[cr][nq+0] = o.x; tile[cr][nq+1] = o.y;
    tile[cr][nq+2] = o.z; tile[cr][nq+3] = o.w;
  }
  if (xtn) {
    __syncthreads();
    #pragma unroll
    for (int p = 0; p < 4; p++) {
      const int nr = (t>>4) + p*16;
      ushort4 o;
      o.x = f2h(tile[cq+0][nr]); o.y = f2h(tile[cq+1][nr]);
      o.z = f2h(tile[cq+2][nr]); o.w = f2h(tile[cq+3][nr]);
      *(ushort4*)&xtn[((long)b*NN + n0+nr)*CC + c0 + cq] = o;
    }
  }
}

// ---------------------------------------------------------------------------
extern "C" void kernel_launch(void* const* d_in, const int* in_sizes, int n_in,
                              void* d_out, int out_size, void* d_ws, size_t ws_size,
                              hipStream_t stream)
{
  const float* x_in   = (const float*)d_in[0];
  const int*   mask   = (const int*)d_in[1];
  const float* conv1w = (const float*)d_in[2];
  const float* conv2w = (const float*)d_in[3];
  const float* bn1g   = (const float*)d_in[4];
  const float* bn1b   = (const float*)d_in[5];
  const float* bn2g   = (const float*)d_in[6];
  const float* bn2b   = (const float*)d_in[7];
  const float* qkw    = (const float*)d_in[8];
  const float* vw     = (const float*)d_in[9];
  const float* vb     = (const float*)d_in[10];
  const float* tw     = (const float*)d_in[11];
  const float* tb     = (const float*)d_in[12];
  const float* bng    = (const float*)d_in[13];
  const float* bnb    = (const float*)d_in[14];
  float* out = (float*)d_out;

  const long BCN = (long)BB*CC*NN;
  const long CN  = (long)CC*NN;
  const long BN  = (long)BB*NN;
  char* p = (char*)d_ws;
  unsigned short* xTa  = (unsigned short*)p; p += BCN*2;
  unsigned short* xTb  = (unsigned short*)p; p += BCN*2;
  unsigned short* qTb  = (unsigned short*)p; p += (long)BB*NN*HH*2;
  unsigned short* xvb  = (unsigned short*)p; p += BCN*2;
  unsigned short* tTh  = (unsigned short*)p; p += BCN*2;
  unsigned short* xrTh = (unsigned short*)p; p += BCN*2;
  float* xbuf  = (float*)p; p += BCN*4;
  float* rmaxb = (float*)p; p += BN*4;
  float* rinvb = (float*)p; p += BN*4;
  float* csumb = (float*)p; p += BN*4;
  float* partb = (float*)p; p += 512L*CC*4;
  float* meanb = (float*)p; p += CC*4;
  float* istdb = (float*)p; p += CC*4;
  unsigned short* wc1 = (unsigned short*)p; p += (long)CC*CC*2;
  unsigned short* wc2 = (unsigned short*)p; p += (long)CC*CC*2;
  unsigned short* wqk = (unsigned short*)p; p += 4L*HH*CC*2;
  unsigned short* wv  = (unsigned short*)p; p += 4L*CC*CC*2;
  unsigned short* wt  = (unsigned short*)p; p += 4L*CC*CC*2;

  const dim3 gT(NN/64, CC/64, BB);
  const dim3 gQ(NN/64, 1, BB);
  const dim3 gRS(NN/64, BB);
  const dim3 blk(256);

  castw_kernel<<<dim3(256), blk, 0, stream>>>(conv1w, wc1, CC*CC, 1.f);
  castw_kernel<<<dim3(256), blk, 0, stream>>>(conv2w, wc2, CC*CC, 1.f);
  castw_kernel<<<dim3(256), blk, 0, stream>>>(qkw, wqk, 4*HH*CC, SQRTL2E);
  castw_kernel<<<dim3(1024), blk, 0, stream>>>(vw, wv, 4*CC*CC, 1.f);
  castw_kernel<<<dim3(1024), blk, 0, stream>>>(tw, wt, 4*CC*CC, 1.f);

  // pre-stage
  tcast_kernel<<<gT, blk, 0, stream>>>(x_in, CN, xTa);
  gemm_xw_kernel<<<gT, blk, 0, stream>>>(xTa, wc1, nullptr, tTh, CC);
  bnstatsA_kernel<<<dim3(256), blk, 0, stream>>>(tTh, partb);
  bnstatsB_kernel<<<dim3(1), dim3(1024), 0, stream>>>(partb, meanb, istdb);
  bnapplyA_kernel<<<dim3(4096), blk, 0, stream>>>(tTh, meanb, istdb, bn1g, bn1b, xTb);
  gemm_xw_kernel<<<gT, blk, 0, stream>>>(xTb, wc2, nullptr, tTh, CC);
  bnstatsA_kernel<<<dim3(256), blk, 0, stream>>>(tTh, partb);
  bnstatsB_kernel<<<dim3(1), dim3(1024), 0, stream>>>(partb, meanb, istdb);
  bnfuse_kernel<<<gT, blk, 0, stream>>>(tTh, meanb, istdb, bn2g, bn2b,
                                        nullptr, 0, xbuf, CN, xTa);

  unsigned short* cur = xTa;
  unsigned short* nxt = xTb;
  for (int i = 0; i < 4; i++) {
    gemm_xw_kernel<<<gQ, blk, 0, stream>>>(cur, wqk + (long)i*HH*CC, nullptr, qTb, HH);
    rowstat_kernel<<<gRS, blk, 0, stream>>>(qTb, mask, rmaxb, rinvb);
    gemm_wx_kernel<<<gT, blk, 0, stream>>>(wv + (long)i*CC*CC, cur, vb + (long)i*CC, xvb);
    yatt_kernel<<<dim3(512), blk, 0, stream>>>(qTb, xvb, mask, rmaxb, rinvb, xrTh, csumb);
    gemm_dxw_kernel<<<gT, blk, 0, stream>>>(cur, xrTh, csumb,
                                            wt + (long)i*CC*CC, tb + (long)i*CC, tTh);
    bnstatsA_kernel<<<dim3(256), blk, 0, stream>>>(tTh, partb);
    bnstatsB_kernel<<<dim3(1), dim3(1024), 0, stream>>>(partb, meanb, istdb);
    const float* resid = (i == 0) ? xbuf : (out + (long)(i-1)*CN);
    const long rstr = (i == 0) ? CN : 4*CN;
    bnfuse_kernel<<<gT, blk, 0, stream>>>(tTh, meanb, istdb,
                                          bng + (long)i*CC, bnb + (long)i*CC,
                                          resid, rstr, out + (long)i*CN, 4*CN,
                                          (i < 3) ? nxt : nullptr);
    unsigned short* tmp = cur; cur = nxt; nxt = tmp;
  }

  (void)in_sizes; (void)n_in; (void)out_size; (void)ws_size;
}

// Round 13
// 802.354 us; speedup vs baseline: 1.6958x; 1.6958x over previous
//
#include <hip/hip_runtime.h>
#include <math.h>

#define BB 16
#define CC 256
#define NN 2048
#define HH 64
#define ATTSC 4096.0f
#define ATTINV (1.0f/4096.0f)
#define SQRTL2E 1.2011224087864498f   // sqrt(log2(e)); q scaled -> S' = S*log2e
#define NEGB (-1.0e30f)
#define POSB (1.0e30f)

typedef _Float16 f16x8 __attribute__((ext_vector_type(8)));
typedef float f32x4 __attribute__((ext_vector_type(4)));

__device__ __forceinline__ f32x4 mfma16(f16x8 a, f16x8 b, f32x4 c) {
  return __builtin_amdgcn_mfma_f32_16x16x32_f16(a, b, c, 0, 0, 0);
}
__device__ __forceinline__ unsigned short f2h(float f) {
  _Float16 h = (_Float16)f;
  return __builtin_bit_cast(unsigned short, h);
}
__device__ __forceinline__ float h2f(unsigned short u) {
  return (float)__builtin_bit_cast(_Float16, u);
}
__device__ __forceinline__ unsigned pkrtz(float a, float b) {
  auto h = __builtin_amdgcn_cvt_pkrtz(a, b);   // __fp16 ext_vector(2)
  return __builtin_bit_cast(unsigned, h);
}
// Swizzled LDS accessor: row stride 128B, byte ^= ((row&7)<<4)  (T2)
__device__ __forceinline__ unsigned short* sp(unsigned short* base, int row, int colh) {
  return (unsigned short*)((char*)base + (row << 7) + (((colh << 1)) ^ ((row & 7) << 4)));
}
__device__ __forceinline__ const unsigned short* spc(const unsigned short* base, int row, int colh) {
  return (const unsigned short*)((const char*)base + (row << 7) + (((colh << 1)) ^ ((row & 7) << 4)));
}

// ---------------------------------------------------------------------------
__global__ __launch_bounds__(256)
void castw_kernel(const float* __restrict__ in, unsigned short* __restrict__ out,
                  int n, float scale)
{
  const int i = blockIdx.x*256 + threadIdx.x;
  if (i < n) out[i] = f2h(in[i]*scale);
}

// ---------------------------------------------------------------------------
// transpose-cast: src fp32 [b][C][N] -> dst f16 [B][N][C]  (input stage only)
// ---------------------------------------------------------------------------
__global__ __launch_bounds__(256)
void tcast_kernel(const float* __restrict__ src, long sstride,
                  unsigned short* __restrict__ dst)
{
  const int b = blockIdx.z, n0 = blockIdx.x*64, c0 = blockIdx.y*64;
  const int t = threadIdx.x;
  __shared__ float tile[64][66];   // [c][n]
  const float* sb = src + (long)b*sstride;
  #pragma unroll
  for (int p = 0; p < 4; p++) {
    const int cr = (t>>4) + p*16;
    const int nq = (t&15)*4;
    const float4 v = *(const float4*)&sb[(long)(c0+cr)*NN + n0 + nq];
    tile[cr][nq+0] = v.x; tile[cr][nq+1] = v.y;
    tile[cr][nq+2] = v.z; tile[cr][nq+3] = v.w;
  }
  __syncthreads();
  unsigned short* db = dst + (long)b*NN*CC;
  #pragma unroll
  for (int p = 0; p < 4; p++) {
    const int nr = (t>>4) + p*16;
    const int cq = (t&15)*4;
    ushort4 o;
    o.x = f2h(tile[cq+0][nr]); o.y = f2h(tile[cq+1][nr]);
    o.z = f2h(tile[cq+2][nr]); o.w = f2h(tile[cq+3][nr]);
    *(ushort4*)&db[(long)(n0+nr)*CC + c0 + cq] = o;
  }
}

// ---------------------------------------------------------------------------
// GEMM (A-major n): D[n][o] = sum_c A[n][c] * W[o][c] (+bias[o]); out f16
// ---------------------------------------------------------------------------
__global__ __launch_bounds__(256)
void gemm_xw_kernel(const unsigned short* __restrict__ A,
                    const unsigned short* __restrict__ W,
                    const float* __restrict__ bias,
                    unsigned short* __restrict__ out, int ocols)
{
  const int n0 = blockIdx.x*64, o0 = blockIdx.y*64, b = blockIdx.z;
  const int t = threadIdx.x;
  const int w = t >> 6, l = t & 63, lr = l & 15, lg = l >> 4;
  const int wr = w >> 1, wc = w & 1;
  __shared__ unsigned short Al[64][72];
  __shared__ unsigned short Bl[64][72];
  const unsigned short* Ab = A + ((long)b*NN + n0)*CC;
  const int srow = t >> 3, sg = t & 7;
  f32x4 acc[2][2];
  #pragma unroll
  for (int i = 0; i < 2; i++)
    #pragma unroll
    for (int j = 0; j < 2; j++) acc[i][j] = f32x4{0.f,0.f,0.f,0.f};

  for (int kt = 0; kt < 4; kt++) {
    const int k0 = kt*64;
    const uint4 a0 = *(const uint4*)&Ab[(long)srow*CC + k0 + sg*8];
    const uint4 a1 = *(const uint4*)&Ab[(long)(srow+32)*CC + k0 + sg*8];
    const uint4 w0 = *(const uint4*)&W[(long)(o0+srow)*CC + k0 + sg*8];
    const uint4 w1 = *(const uint4*)&W[(long)(o0+srow+32)*CC + k0 + sg*8];
    __syncthreads();
    *(uint4*)&Al[srow][sg*8] = a0;  *(uint4*)&Al[srow+32][sg*8] = a1;
    *(uint4*)&Bl[srow][sg*8] = w0;  *(uint4*)&Bl[srow+32][sg*8] = w1;
    __syncthreads();
    #pragma unroll
    for (int kf = 0; kf < 2; kf++) {
      f16x8 af0 = *(const f16x8*)&Al[wr*32 + lr]     [kf*32 + lg*8];
      f16x8 af1 = *(const f16x8*)&Al[wr*32 + 16 + lr][kf*32 + lg*8];
      f16x8 bf0 = *(const f16x8*)&Bl[wc*32 + lr]     [kf*32 + lg*8];
      f16x8 bf1 = *(const f16x8*)&Bl[wc*32 + 16 + lr][kf*32 + lg*8];
      acc[0][0] = mfma16(af0, bf0, acc[0][0]);
      acc[0][1] = mfma16(af0, bf1, acc[0][1]);
      acc[1][0] = mfma16(af1, bf0, acc[1][0]);
      acc[1][1] = mfma16(af1, bf1, acc[1][1]);
    }
  }
  #pragma unroll
  for (int j = 0; j < 2; j++) {
    const int oc = o0 + wc*32 + j*16 + lr;
    const float bo = bias ? bias[oc] : 0.f;
    #pragma unroll
    for (int i = 0; i < 2; i++) {
      const int nb = n0 + wr*32 + i*16 + lg*4;
      #pragma unroll
      for (int r = 0; r < 4; r++)
        out[((long)b*NN + nb + r)*ocols + oc] = f2h(acc[i][j][r] + bo);
    }
  }
}

// ---------------------------------------------------------------------------
// GEMM with fused diff: A[n][c] = X[n][c] - XR[n][c]*inv(n);
// inv = 1/(1e-9+csum[n]). D[n][o] = sum_c A*W + bias -> out f16 [B][N][CC]
// ---------------------------------------------------------------------------
__global__ __launch_bounds__(256)
void gemm_dxw_kernel(const unsigned short* __restrict__ X,
                     const unsigned short* __restrict__ XR,
                     const float* __restrict__ csumv,
                     const unsigned short* __restrict__ W,
                     const float* __restrict__ bias,
                     unsigned short* __restrict__ out)
{
  const int n0 = blockIdx.x*64, o0 = blockIdx.y*64, b = blockIdx.z;
  const int t = threadIdx.x;
  const int w = t >> 6, l = t & 63, lr = l & 15, lg = l >> 4;
  const int wr = w >> 1, wc = w & 1;
  __shared__ unsigned short Al[64][72];
  __shared__ unsigned short Bl[64][72];
  const unsigned short* Xb  = X  + ((long)b*NN + n0)*CC;
  const unsigned short* XRb = XR + ((long)b*NN + n0)*CC;
  const int srow = t >> 3, sg = t & 7;
  const long nrow0 = (long)b*NN + n0 + srow;
  const float inv0 = 1.f/(1e-9f + csumv[nrow0]);
  const float inv1 = 1.f/(1e-9f + csumv[nrow0+32]);
  f32x4 acc[2][2];
  #pragma unroll
  for (int i = 0; i < 2; i++)
    #pragma unroll
    for (int j = 0; j < 2; j++) acc[i][j] = f32x4{0.f,0.f,0.f,0.f};

  for (int kt = 0; kt < 4; kt++) {
    const int k0 = kt*64;
    const uint4 xa  = *(const uint4*)&Xb [(long)srow*CC + k0 + sg*8];
    const uint4 xra = *(const uint4*)&XRb[(long)srow*CC + k0 + sg*8];
    const uint4 xb_ = *(const uint4*)&Xb [(long)(srow+32)*CC + k0 + sg*8];
    const uint4 xrb = *(const uint4*)&XRb[(long)(srow+32)*CC + k0 + sg*8];
    const uint4 w0 = *(const uint4*)&W[(long)(o0+srow)*CC + k0 + sg*8];
    const uint4 w1 = *(const uint4*)&W[(long)(o0+srow+32)*CC + k0 + sg*8];
    uint4 da, db_;
    {
      const unsigned short* xs = (const unsigned short*)&xa;
      const unsigned short* rs = (const unsigned short*)&xra;
      unsigned short* ds = (unsigned short*)&da;
      #pragma unroll
      for (int j = 0; j < 8; j++) ds[j] = f2h(h2f(xs[j]) - h2f(rs[j])*inv0);
      xs = (const unsigned short*)&xb_;
      rs = (const unsigned short*)&xrb;
      ds = (unsigned short*)&db_;
      #pragma unroll
      for (int j = 0; j < 8; j++) ds[j] = f2h(h2f(xs[j]) - h2f(rs[j])*inv1);
    }
    __syncthreads();
    *(uint4*)&Al[srow][sg*8] = da;  *(uint4*)&Al[srow+32][sg*8] = db_;
    *(uint4*)&Bl[srow][sg*8] = w0;  *(uint4*)&Bl[srow+32][sg*8] = w1;
    __syncthreads();
    #pragma unroll
    for (int kf = 0; kf < 2; kf++) {
      f16x8 af0 = *(const f16x8*)&Al[wr*32 + lr]     [kf*32 + lg*8];
      f16x8 af1 = *(const f16x8*)&Al[wr*32 + 16 + lr][kf*32 + lg*8];
      f16x8 bf0 = *(const f16x8*)&Bl[wc*32 + lr]     [kf*32 + lg*8];
      f16x8 bf1 = *(const f16x8*)&Bl[wc*32 + 16 + lr][kf*32 + lg*8];
      acc[0][0] = mfma16(af0, bf0, acc[0][0]);
      acc[0][1] = mfma16(af0, bf1, acc[0][1]);
      acc[1][0] = mfma16(af1, bf0, acc[1][0]);
      acc[1][1] = mfma16(af1, bf1, acc[1][1]);
    }
  }
  #pragma unroll
  for (int j = 0; j < 2; j++) {
    const int oc = o0 + wc*32 + j*16 + lr;
    const float bo = bias[oc];
    #pragma unroll
    for (int i = 0; i < 2; i++) {
      const int nb = n0 + wr*32 + i*16 + lg*4;
      #pragma unroll
      for (int r = 0; r < 4; r++)
        out[((long)b*NN + nb + r)*CC + oc] = f2h(acc[i][j][r] + bo);
    }
  }
}

// ---------------------------------------------------------------------------
// GEMM (W-major o): out[o][n] = sum_c W[o][c]*X[n][c] + bias[o]; f16 [B][CC][NN]
// ---------------------------------------------------------------------------
__global__ __launch_bounds__(256)
void gemm_wx_kernel(const unsigned short* __restrict__ W,
                    const unsigned short* __restrict__ X,
                    const float* __restrict__ bias,
                    unsigned short* __restrict__ out)
{
  const int n0 = blockIdx.x*64, o0 = blockIdx.y*64, b = blockIdx.z;
  const int t = threadIdx.x;
  const int w = t >> 6, l = t & 63, lr = l & 15, lg = l >> 4;
  const int wr = w >> 1, wc = w & 1;
  __shared__ unsigned short Al[64][72];
  __shared__ unsigned short Bl[64][72];
  const unsigned short* Xb = X + ((long)b*NN + n0)*CC;
  const int srow = t >> 3, sg = t & 7;
  f32x4 acc[2][2];
  #pragma unroll
  for (int i = 0; i < 2; i++)
    #pragma unroll
    for (int j = 0; j < 2; j++) acc[i][j] = f32x4{0.f,0.f,0.f,0.f};

  for (int kt = 0; kt < 4; kt++) {
    const int k0 = kt*64;
    const uint4 w0 = *(const uint4*)&W[(long)(o0+srow)*CC + k0 + sg*8];
    const uint4 w1 = *(const uint4*)&W[(long)(o0+srow+32)*CC + k0 + sg*8];
    const uint4 x0 = *(const uint4*)&Xb[(long)srow*CC + k0 + sg*8];
    const uint4 x1 = *(const uint4*)&Xb[(long)(srow+32)*CC + k0 + sg*8];
    __syncthreads();
    *(uint4*)&Al[srow][sg*8] = w0;  *(uint4*)&Al[srow+32][sg*8] = w1;
    *(uint4*)&Bl[srow][sg*8] = x0;  *(uint4*)&Bl[srow+32][sg*8] = x1;
    __syncthreads();
    #pragma unroll
    for (int kf = 0; kf < 2; kf++) {
      f16x8 af0 = *(const f16x8*)&Al[wr*32 + lr]     [kf*32 + lg*8];
      f16x8 af1 = *(const f16x8*)&Al[wr*32 + 16 + lr][kf*32 + lg*8];
      f16x8 bf0 = *(const f16x8*)&Bl[wc*32 + lr]     [kf*32 + lg*8];
      f16x8 bf1 = *(const f16x8*)&Bl[wc*32 + 16 + lr][kf*32 + lg*8];
      acc[0][0] = mfma16(af0, bf0, acc[0][0]);
      acc[0][1] = mfma16(af0, bf1, acc[0][1]);
      acc[1][0] = mfma16(af1, bf0, acc[1][0]);
      acc[1][1] = mfma16(af1, bf1, acc[1][1]);
    }
  }
  #pragma unroll
  for (int j = 0; j < 2; j++) {
    const int nc = n0 + wc*32 + j*16 + lr;
    #pragma unroll
    for (int i = 0; i < 2; i++) {
      #pragma unroll
      for (int r = 0; r < 4; r++) {
        const int oc = o0 + wr*32 + i*16 + lg*4 + r;
        out[((long)b*CC + oc)*NN + nc] = f2h(acc[i][j][r] + bias[oc]);
      }
    }
  }
}

// ---------------------------------------------------------------------------
// rowstat (exp2 domain): per (b,n) over all m: log2-domain max & 1/sum of
// exp2(masked S'[n,m]). Dead rows -> rmax=+1e30.
// ---------------------------------------------------------------------------
__global__ __launch_bounds__(256)
void rowstat_kernel(const unsigned short* __restrict__ qT, const int* __restrict__ mask,
                    float* __restrict__ rmax, float* __restrict__ rinv)
{
  const int b = blockIdx.y, n0 = blockIdx.x*64;
  const int t = threadIdx.x, w = t>>6, l = t&63, lr = l&15, lg = l>>4;
  __shared__ unsigned short qs[64*64];
  __shared__ int ml[64];
  const int srow = t>>3, sg = t&7;
  const unsigned short* qbase = qT + (long)b*NN*HH;
  *(uint4*)sp(qs, srow,    sg*8) = *(const uint4*)&qbase[(long)(n0+srow)*HH + sg*8];
  *(uint4*)sp(qs, srow+32, sg*8) = *(const uint4*)&qbase[(long)(n0+srow+32)*HH + sg*8];
  int maskn[4];
  #pragma unroll
  for (int r = 0; r < 4; r++) maskn[r] = mask[(long)b*NN + n0 + w*16 + lg*4 + r];
  __syncthreads();
  f16x8 af0 = *(const f16x8*)spc(qs, w*16 + lr, lg*8);
  f16x8 af1 = *(const f16x8*)spc(qs, w*16 + lr, 32 + lg*8);
  float mx[4], sm[4];
  #pragma unroll
  for (int r = 0; r < 4; r++) { mx[r] = -INFINITY; sm[r] = 0.f; }

  for (int m0 = 0; m0 < NN; m0 += 64) {
    __syncthreads();
    *(uint4*)sp(qs, srow,    sg*8) = *(const uint4*)&qbase[(long)(m0+srow)*HH + sg*8];
    *(uint4*)sp(qs, srow+32, sg*8) = *(const uint4*)&qbase[(long)(m0+srow+32)*HH + sg*8];
    if (t < 64) ml[t] = mask[(long)b*NN + m0 + t];
    __syncthreads();
    float sv[4][4];
    #pragma unroll
    for (int tm = 0; tm < 4; tm++) {
      f32x4 s = f32x4{0.f,0.f,0.f,0.f};
      s = mfma16(af0, *(const f16x8*)spc(qs, tm*16 + lr, lg*8),      s);
      s = mfma16(af1, *(const f16x8*)spc(qs, tm*16 + lr, 32 + lg*8), s);
      const int cm = ml[tm*16 + lr];
      #pragma unroll
      for (int r = 0; r < 4; r++) sv[tm][r] = (maskn[r] && cm) ? s[r] : NEGB;
    }
    #pragma unroll
    for (int r = 0; r < 4; r++) {
      const float tmx = fmaxf(fmaxf(sv[0][r], sv[1][r]), fmaxf(sv[2][r], sv[3][r]));
      const float nm  = fmaxf(mx[r], tmx);
      sm[r] = sm[r]*exp2f(mx[r]-nm)
            + exp2f(sv[0][r]-nm) + exp2f(sv[1][r]-nm)
            + exp2f(sv[2][r]-nm) + exp2f(sv[3][r]-nm);
      mx[r] = nm;
    }
  }
  #pragma unroll
  for (int off = 1; off < 16; off <<= 1) {
    #pragma unroll
    for (int r = 0; r < 4; r++) {
      const float om = __shfl_xor(mx[r], off, 64);
      const float os = __shfl_xor(sm[r], off, 64);
      const float nm = fmaxf(mx[r], om);
      sm[r] = sm[r]*exp2f(mx[r]-nm) + os*exp2f(om-nm);
      mx[r] = nm;
    }
  }
  if (lr == 0) {
    #pragma unroll
    for (int r = 0; r < 4; r++) {
      const long idx = (long)b*NN + n0 + w*16 + lg*4 + r;
      rmax[idx] = maskn[r] ? mx[r] : POSB;   // dead row: exp2(s-POSB)=0 in yatt
      rinv[idx] = 1.f/sm[r];
    }
  }
}

// ---------------------------------------------------------------------------
// yatt: R6 schedule (grid 512, m-tile 64, full c, 3 barriers/chunk) with the
// swap's micro-wins; qm B-frags in a third swizzled LDS tile (keeps VGPR
// ~100-110, under the 128 cliff). NO min-waves clamp: R12's (256,4) forced
// VGPR=64 -> 330MB scratch spill. Natural allocation is the right point.
// ---------------------------------------------------------------------------
__global__ __launch_bounds__(256)
void yatt_kernel(const unsigned short* __restrict__ qT, const unsigned short* __restrict__ xv,
                 const int* __restrict__ mask, const float* __restrict__ rmax,
                 const float* __restrict__ rinv, unsigned short* __restrict__ xrTh,
                 float* __restrict__ csum)
{
  const int bid = blockIdx.x;
  const int swz = (bid & 7)*64 + (bid >> 3);   // 512 = 8 XCD x 64
  const int b  = swz >> 5;
  const int m0 = (swz & 31) * 64;
  const int t = threadIdx.x, w = t>>6, l = t&63, lr = l&15, lg = l>>4;

  __shared__ unsigned short qm[64*64];   // 8 KB swizzled [m][h], block-constant
  __shared__ unsigned short qn[64*64];   // 8 KB swizzled [n][h]
  __shared__ unsigned short at[64*64];   // 8 KB swizzled [m][n]
  __shared__ float csred[4][4][16];

  const unsigned short* qbase = qT + (long)b*NN*HH;
  const unsigned short* xvb = xv + (long)b*CC*NN;
  const int srow = t>>3, sg = t&7;

  // stage qm once + column-mask (block-constant)
  *(uint4*)sp(qm, srow,    sg*8) = *(const uint4*)&qbase[(long)(m0+srow)*HH + sg*8];
  *(uint4*)sp(qm, srow+32, sg*8) = *(const uint4*)&qbase[(long)(m0+srow+32)*HH + sg*8];
  float mcf[4];
  #pragma unroll
  for (int tm = 0; tm < 4; tm++)
    mcf[tm] = mask[(long)b*NN + m0 + tm*16 + lr] ? 1.f : 0.f;

  f32x4 acc[4][4];
  #pragma unroll
  for (int mi = 0; mi < 4; mi++)
    #pragma unroll
    for (int ci = 0; ci < 4; ci++) acc[mi][ci] = f32x4{0.f,0.f,0.f,0.f};
  float cs[4] = {0.f, 0.f, 0.f, 0.f};
  const int nb = w*16 + lg*4;    // thread's 4 n rows within chunk

  for (int nc = 0; nc < NN; nc += 64) {
    __syncthreads();   // prev S (qn readers) + prev PV (at readers) done; qm staged
    *(uint4*)sp(qn, srow,    sg*8) = *(const uint4*)&qbase[(long)(nc+srow)*HH + sg*8];
    *(uint4*)sp(qn, srow+32, sg*8) = *(const uint4*)&qbase[(long)(nc+srow+32)*HH + sg*8];
    const float4 rm4 = *(const float4*)&rmax[(long)b*NN + nc + nb];
    const float4 ri4 = *(const float4*)&rinv[(long)b*NN + nc + nb];
    const int4   mn4 = *(const int4*)&mask[(long)b*NN + nc + nb];
    // xv B-frags issued early (T14); L2-resident, latency hides under staging
    f16x8 xb0[4], xb1[4];
    #pragma unroll
    for (int ci = 0; ci < 4; ci++) {
      const unsigned short* xp = &xvb[(long)(w*64 + ci*16 + lr)*NN + nc];
      xb0[ci] = *(const f16x8*)(xp + lg*8);
      xb1[ci] = *(const f16x8*)(xp + 32 + lg*8);
    }
    __syncthreads();   // qn staged
    const float rmv[4] = {rm4.x, rm4.y, rm4.z, rm4.w};
    const float rvs[4] = {ri4.x*ATTSC, ri4.y*ATTSC, ri4.z*ATTSC, ri4.w*ATTSC};
    const float dsc[4] = {mn4.x ? 0.f : rvs[0], mn4.y ? 0.f : rvs[1],
                          mn4.z ? 0.f : rvs[2], mn4.w ? 0.f : rvs[3]};
    // S: D[n][m] via A-frag = qn (wave's 16 n-rows), B-frag = qm from LDS
    const f16x8 a0 = *(const f16x8*)spc(qn, w*16 + lr, lg*8);
    const f16x8 a1 = *(const f16x8*)spc(qn, w*16 + lr, 32 + lg*8);
    #pragma unroll
    for (int tm = 0; tm < 4; tm++) {
      const f16x8 bq0 = *(const f16x8*)spc(qm, tm*16 + lr, lg*8);
      const f16x8 bq1 = *(const f16x8*)spc(qm, tm*16 + lr, 32 + lg*8);
      f32x4 s = mfma16(a0, bq0, f32x4{0.f,0.f,0.f,0.f});
      s = mfma16(a1, bq1, s);
      const float c0 = rvs[0]*mcf[tm], c1 = rvs[1]*mcf[tm];
      const float c2 = rvs[2]*mcf[tm], c3 = rvs[3]*mcf[tm];
      const float a0_ = exp2f(s[0]-rmv[0])*c0 + dsc[0];
      const float a1_ = exp2f(s[1]-rmv[1])*c1 + dsc[1];
      const float a2_ = exp2f(s[2]-rmv[2])*c2 + dsc[2];
      const float a3_ = exp2f(s[3]-rmv[3])*c3 + dsc[3];
      cs[tm] += (a0_ + a1_) + (a2_ + a3_);
      uint2 pk;
      pk.x = pkrtz(a0_, a1_);
      pk.y = pkrtz(a2_, a3_);
      *(uint2*)sp(at, tm*16 + lr, nb) = pk;   // 4 consecutive n at fixed m
    }
    __syncthreads();   // at ready
    // PV: acc[m][c] += at[m][n'] * xv[c][n']
    #pragma unroll
    for (int mi = 0; mi < 4; mi++) {
      const f16x8 aa0 = *(const f16x8*)spc(at, mi*16 + lr, lg*8);
      const f16x8 aa1 = *(const f16x8*)spc(at, mi*16 + lr, 32 + lg*8);
      #pragma unroll
      for (int ci = 0; ci < 4; ci++) {
        acc[mi][ci] = mfma16(aa0, xb0[ci], acc[mi][ci]);
        acc[mi][ci] = mfma16(aa1, xb1[ci], acc[mi][ci]);
      }
    }
  }

  #pragma unroll
  for (int mi = 0; mi < 4; mi++)
    #pragma unroll
    for (int ci = 0; ci < 4; ci++)
      #pragma unroll
      for (int r = 0; r < 4; r++)
        xrTh[((long)b*NN + m0 + mi*16 + lg*4 + r)*CC + w*64 + ci*16 + lr] =
            f2h(acc[mi][ci][r] * ATTINV);

  #pragma unroll
  for (int tm = 0; tm < 4; tm++) {
    cs[tm] += __shfl_xor(cs[tm], 16, 64);
    cs[tm] += __shfl_xor(cs[tm], 32, 64);
    if (lg == 0) csred[tm][w][lr] = cs[tm];
  }
  __syncthreads();
  if (t < 64) {
    const int tm = t >> 4, mr = t & 15;
    const float v = csred[tm][0][mr] + csred[tm][1][mr]
                  + csred[tm][2][mr] + csred[tm][3][mr];
    csum[(long)b*NN + m0 + tm*16 + mr] = v * ATTINV;
  }
}

// ---------------------------------------------------------------------------
// BN stats over [B*N][C] f16, two-stage deterministic
// ---------------------------------------------------------------------------
__global__ __launch_bounds__(256)
void bnstatsA_kernel(const unsigned short* __restrict__ tTh, float* __restrict__ part)
{
  const int k = blockIdx.x;
  const int c = threadIdx.x;
  float s = 0.f, sq = 0.f;
  const long r0 = (long)k*128;
  for (int r = 0; r < 128; r++) {
    const float v = h2f(tTh[(r0 + r)*CC + c]);
    s += v; sq += v*v;
  }
  part[(long)k*CC + c] = s;
  part[(long)(256 + k)*CC + c] = sq;
}

__global__ __launch_bounds__(1024)
void bnstatsB_kernel(const float* __restrict__ part,
                     float* __restrict__ mean, float* __restrict__ istd)
{
  const int t = threadIdx.x, c = t & 255, q = t >> 8;
  float s = 0.f, sq = 0.f;
  for (int k = q*64; k < q*64 + 64; k++) {
    s  += part[(long)k*CC + c];
    sq += part[(long)(256 + k)*CC + c];
  }
  __shared__ float ls[4][256], lq[4][256];
  ls[q][c] = s; lq[q][c] = sq;
  __syncthreads();
  if (q == 0) {
    s  = ls[0][c] + ls[1][c] + ls[2][c] + ls[3][c];
    sq = lq[0][c] + lq[1][c] + lq[2][c] + lq[3][c];
    const float mu = s / (float)(BB*NN);
    mean[c] = mu;
    istd[c] = rsqrtf(sq/(float)(BB*NN) - mu*mu + 1e-5f);
  }
}

// ---------------------------------------------------------------------------
// bnapplyA: xTo[p][c] = f16(relu(bn(tTh[p][c])))
// ---------------------------------------------------------------------------
__global__ __launch_bounds__(256)
void bnapplyA_kernel(const unsigned short* __restrict__ tTh, const float* __restrict__ mean,
                     const float* __restrict__ istd, const float* __restrict__ g,
                     const float* __restrict__ bt, unsigned short* __restrict__ xTo)
{
  __shared__ float sc[CC], sh[CC];
  const int t = threadIdx.x;
  {
    const float is = istd[t], gg = g[t];
    sc[t] = is*gg; sh[t] = bt[t] - mean[t]*is*gg;
  }
  __syncthreads();
  const long i = (long)blockIdx.x*256 + t;
  const long base = i*8;
  const int c8 = (int)(base & 255);
  const uint4 v = *(const uint4*)&tTh[base];
  const unsigned short* hs = (const unsigned short*)&v;
  uint4 ou;
  unsigned short* os = (unsigned short*)&ou;
  #pragma unroll
  for (int j = 0; j < 8; j++)
    os[j] = f2h(fmaxf(h2f(hs[j])*sc[c8+j] + sh[c8+j], 0.f));
  *(uint4*)&xTo[base] = ou;
}

// ---------------------------------------------------------------------------
// bnfuse: tTh f16 [n][c] -> out fp32 [c][n] = relu(bn)+resid, plus optional
// xtn f16 [n][c] for the next layer.
// ---------------------------------------------------------------------------
__global__ __launch_bounds__(256)
void bnfuse_kernel(const unsigned short* __restrict__ tTh, const float* __restrict__ mean,
                   const float* __restrict__ istd, const float* __restrict__ g,
                   const float* __restrict__ bt, const float* __restrict__ resid,
                   long rstride, float* __restrict__ outp, long ostride,
                   unsigned short* __restrict__ xtn)
{
  const int b = blockIdx.z, n0 = blockIdx.x*64, c0 = blockIdx.y*64;
  const int t = threadIdx.x;
  __shared__ float tile[64][66];
  const unsigned short* tb_ = tTh + ((long)b*NN + n0)*CC;
  const int cq = (t&15)*4;
  float scv[4], shv[4];
  #pragma unroll
  for (int j = 0; j < 4; j++) {
    const int c = c0 + cq + j;
    const float is = istd[c], gg = g[c];
    scv[j] = is*gg; shv[j] = bt[c] - mean[c]*is*gg;
  }
  #pragma unroll
  for (int p = 0; p < 4; p++) {
    const int nr = (t>>4) + p*16;
    const ushort4 v = *(const ushort4*)&tb_[(long)nr*CC + c0 + cq];
    tile[cq+0][nr] = fmaxf(h2f(v.x)*scv[0] + shv[0], 0.f);
    tile[cq+1][nr] = fmaxf(h2f(v.y)*scv[1] + shv[1], 0.f);
    tile[cq+2][nr] = fmaxf(h2f(v.z)*scv[2] + shv[2], 0.f);
    tile[cq+3][nr] = fmaxf(h2f(v.w)*scv[3] + shv[3], 0.f);
  }
  __syncthreads();
  const int nq = (t&15)*4;
  #pragma unroll
  for (int p = 0; p < 4; p++) {
    const int cr = (t>>4) + p*16;
    float4 o;
    o.x = tile[cr][nq+0]; o.y = tile[cr][nq+1];
    o.z = tile[cr][nq+2]; o.w = tile[cr][nq+3];
    if (resid) {
      const float4 rv = *(const float4*)&resid[(long)b*rstride + (long)(c0+cr)*NN + n0 + nq];
      o.x += rv.x; o.y += rv.y; o.z += rv.z; o.w += rv.w;
    }
    *(float4*)&outp[(long)b*ostride + (long)(c0+cr)*NN + n0 + nq] = o;
    tile[cr][nq+0] = o.x; tile[cr][nq+1] = o.y;
    tile[cr][nq+2] = o.z; tile[cr][nq+3] = o.w;
  }
  if (xtn) {
    __syncthreads();
    #pragma unroll
    for (int p = 0; p < 4; p++) {
      const int nr = (t>>4) + p*16;
      ushort4 o;
      o.x = f2h(tile[cq+0][nr]); o.y = f2h(tile[cq+1][nr]);
      o.z = f2h(tile[cq+2][nr]); o.w = f2h(tile[cq+3][nr]);
      *(ushort4*)&xtn[((long)b*NN + n0+nr)*CC + c0 + cq] = o;
    }
  }
}

// ---------------------------------------------------------------------------
extern "C" void kernel_launch(void* const* d_in, const int* in_sizes, int n_in,
                              void* d_out, int out_size, void* d_ws, size_t ws_size,
                              hipStream_t stream)
{
  const float* x_in   = (const float*)d_in[0];
  const int*   mask   = (const int*)d_in[1];
  const float* conv1w = (const float*)d_in[2];
  const float* conv2w = (const float*)d_in[3];
  const float* bn1g   = (const float*)d_in[4];
  const float* bn1b   = (const float*)d_in[5];
  const float* bn2g   = (const float*)d_in[6];
  const float* bn2b   = (const float*)d_in[7];
  const float* qkw    = (const float*)d_in[8];
  const float* vw     = (const float*)d_in[9];
  const float* vb     = (const float*)d_in[10];
  const float* tw     = (const float*)d_in[11];
  const float* tb     = (const float*)d_in[12];
  const float* bng    = (const float*)d_in[13];
  const float* bnb    = (const float*)d_in[14];
  float* out = (float*)d_out;

  const long BCN = (long)BB*CC*NN;
  const long CN  = (long)CC*NN;
  const long BN  = (long)BB*NN;
  char* p = (char*)d_ws;
  unsigned short* xTa  = (unsigned short*)p; p += BCN*2;
  unsigned short* xTb  = (unsigned short*)p; p += BCN*2;
  unsigned short* qTb  = (unsigned short*)p; p += (long)BB*NN*HH*2;
  unsigned short* xvb  = (unsigned short*)p; p += BCN*2;
  unsigned short* tTh  = (unsigned short*)p; p += BCN*2;
  unsigned short* xrTh = (unsigned short*)p; p += BCN*2;
  float* xbuf  = (float*)p; p += BCN*4;
  float* rmaxb = (float*)p; p += BN*4;
  float* rinvb = (float*)p; p += BN*4;
  float* csumb = (float*)p; p += BN*4;
  float* partb = (float*)p; p += 512L*CC*4;
  float* meanb = (float*)p; p += CC*4;
  float* istdb = (float*)p; p += CC*4;
  unsigned short* wc1 = (unsigned short*)p; p += (long)CC*CC*2;
  unsigned short* wc2 = (unsigned short*)p; p += (long)CC*CC*2;
  unsigned short* wqk = (unsigned short*)p; p += 4L*HH*CC*2;
  unsigned short* wv  = (unsigned short*)p; p += 4L*CC*CC*2;
  unsigned short* wt  = (unsigned short*)p; p += 4L*CC*CC*2;

  const dim3 gT(NN/64, CC/64, BB);
  const dim3 gQ(NN/64, 1, BB);
  const dim3 gRS(NN/64, BB);
  const dim3 blk(256);

  castw_kernel<<<dim3(256), blk, 0, stream>>>(conv1w, wc1, CC*CC, 1.f);
  castw_kernel<<<dim3(256), blk, 0, stream>>>(conv2w, wc2, CC*CC, 1.f);
  castw_kernel<<<dim3(256), blk, 0, stream>>>(qkw, wqk, 4*HH*CC, SQRTL2E);
  castw_kernel<<<dim3(1024), blk, 0, stream>>>(vw, wv, 4*CC*CC, 1.f);
  castw_kernel<<<dim3(1024), blk, 0, stream>>>(tw, wt, 4*CC*CC, 1.f);

  // pre-stage
  tcast_kernel<<<gT, blk, 0, stream>>>(x_in, CN, xTa);
  gemm_xw_kernel<<<gT, blk, 0, stream>>>(xTa, wc1, nullptr, tTh, CC);
  bnstatsA_kernel<<<dim3(256), blk, 0, stream>>>(tTh, partb);
  bnstatsB_kernel<<<dim3(1), dim3(1024), 0, stream>>>(partb, meanb, istdb);
  bnapplyA_kernel<<<dim3(4096), blk, 0, stream>>>(tTh, meanb, istdb, bn1g, bn1b, xTb);
  gemm_xw_kernel<<<gT, blk, 0, stream>>>(xTb, wc2, nullptr, tTh, CC);
  bnstatsA_kernel<<<dim3(256), blk, 0, stream>>>(tTh, partb);
  bnstatsB_kernel<<<dim3(1), dim3(1024), 0, stream>>>(partb, meanb, istdb);
  bnfuse_kernel<<<gT, blk, 0, stream>>>(tTh, meanb, istdb, bn2g, bn2b,
                                        nullptr, 0, xbuf, CN, xTa);

  unsigned short* cur = xTa;
  unsigned short* nxt = xTb;
  for (int i = 0; i < 4; i++) {
    gemm_xw_kernel<<<gQ, blk, 0, stream>>>(cur, wqk + (long)i*HH*CC, nullptr, qTb, HH);
    rowstat_kernel<<<gRS, blk, 0, stream>>>(qTb, mask, rmaxb, rinvb);
    gemm_wx_kernel<<<gT, blk, 0, stream>>>(wv + (long)i*CC*CC, cur, vb + (long)i*CC, xvb);
    yatt_kernel<<<dim3(512), blk, 0, stream>>>(qTb, xvb, mask, rmaxb, rinvb, xrTh, csumb);
    gemm_dxw_kernel<<<gT, blk, 0, stream>>>(cur, xrTh, csumb,
                                            wt + (long)i*CC*CC, tb + (long)i*CC, tTh);
    bnstatsA_kernel<<<dim3(256), blk, 0, stream>>>(tTh, partb);
    bnstatsB_kernel<<<dim3(1), dim3(1024), 0, stream>>>(partb, meanb, istdb);
    const float* resid = (i == 0) ? xbuf : (out + (long)(i-1)*CN);
    const long rstr = (i == 0) ? CN : 4*CN;
    bnfuse_kernel<<<gT, blk, 0, stream>>>(tTh, meanb, istdb,
                                          bng + (long)i*CC, bnb + (long)i*CC,
                                          resid, rstr, out + (long)i*CN, 4*CN,
                                          (i < 3) ? nxt : nullptr);
    unsigned short* tmp = cur; cur = nxt; nxt = tmp;
  }

  (void)in_sizes; (void)n_in; (void)out_size; (void)ws_size;
}